// Round 6
// baseline (1536.154 us; speedup 1.0000x reference)
//
#include <hip/hip_runtime.h>
#include <math.h>

// Problem constants (fixed by the reference)
#define NN   100000
#define FIN  1024
#define HIDN 16
#define CCH  64
#define EE   3200000
#define BNEPS 1e-5f
#define NB   ((NN + 255) / 256)   // 391 scan blocks
#define NPART 8                   // XCD count
#define PSZ  (NN / NPART)         // 12500 nodes per partition

// ---------------------------------------------------------------------------
// k_hist: XCD-partitioned in-degree histogram (atomics stay in one XCD's L2)
// ---------------------------------------------------------------------------
__global__ __launch_bounds__(256) void k_hist(const int* __restrict__ ei,
                                              unsigned* __restrict__ deg) {
  int p = blockIdx.x & 7;
  int blk = blockIdx.x >> 3;
  int nblk = gridDim.x >> 3;
  int lo = p * PSZ, hi = lo + PSZ;
  for (int e = blk * 256 + threadIdx.x; e < EE; e += nblk * 256) {
    int d = ei[EE + e];
    if (d >= lo && d < hi) atomicAdd(&deg[d], 1u);
  }
}

// ---------------------------------------------------------------------------
// exclusive scan of deg -> rowptr (+ cur copy, + dis = rsqrt(deg+1))
// ---------------------------------------------------------------------------
__global__ __launch_bounds__(256) void k_scan_part(const unsigned* __restrict__ deg,
                                                   unsigned* __restrict__ exc,
                                                   unsigned* __restrict__ bsum) {
  __shared__ unsigned s[256];
  int t = threadIdx.x, i = blockIdx.x * 256 + t;
  unsigned v = (i < NN) ? deg[i] : 0u;
  s[t] = v;
  __syncthreads();
#pragma unroll
  for (int off = 1; off < 256; off <<= 1) {
    unsigned u = (t >= off) ? s[t - off] : 0u;
    __syncthreads();
    s[t] += u;
    __syncthreads();
  }
  if (i < NN) exc[i] = s[t] - v;
  if (t == 255) bsum[blockIdx.x] = s[255];
}

__global__ __launch_bounds__(512) void k_scan_boff(const unsigned* __restrict__ bsum,
                                                   unsigned* __restrict__ boff) {
  __shared__ unsigned s[512];
  int t = threadIdx.x;
  unsigned v = (t < NB) ? bsum[t] : 0u;
  s[t] = v;
  __syncthreads();
#pragma unroll
  for (int off = 1; off < 512; off <<= 1) {
    unsigned u = (t >= off) ? s[t - off] : 0u;
    __syncthreads();
    s[t] += u;
    __syncthreads();
  }
  if (t < NB) boff[t] = s[t] - v;
}

__global__ __launch_bounds__(256) void k_scan_final(const unsigned* __restrict__ exc,
                                                    const unsigned* __restrict__ boff,
                                                    const unsigned* __restrict__ deg,
                                                    int* __restrict__ rowptr,
                                                    int* __restrict__ cur,
                                                    float* __restrict__ dis) {
  int i = blockIdx.x * 256 + threadIdx.x;
  if (i < NN) {
    int r = (int)(boff[i >> 8] + exc[i]);
    rowptr[i] = r;
    cur[i] = r;
    dis[i] = rsqrtf((float)(deg[i] + 1u));
  } else if (i == NN) {
    rowptr[NN] = EE;
  }
}

// ---------------------------------------------------------------------------
// k_place: XCD-partitioned bucket placement (cur + perm slices L2-local)
// ---------------------------------------------------------------------------
__global__ __launch_bounds__(256) void k_place(const int* __restrict__ ei,
                                               int* __restrict__ cur,
                                               int* __restrict__ perm) {
  int p = blockIdx.x & 7;
  int blk = blockIdx.x >> 3;
  int nblk = gridDim.x >> 3;
  int lo = p * PSZ, hi = lo + PSZ;
  for (int e = blk * 256 + threadIdx.x; e < EE; e += nblk * 256) {
    int d = ei[EE + e];
    if (d >= lo && d < hi) {
      int s = ei[e];
      int slot = atomicAdd(&cur[d], 1);
      perm[slot] = s;
    }
  }
}

// ---------------------------------------------------------------------------
// k_gemm1: xw1s[N,16] = (x[N,1024] @ w1[1024,16]) * dis_i  (pre-scaled)
// SOFTWARE-PIPELINED: group g+1's 64 x-loads are issued into a second
// register buffer BEFORE group g's FMA+butterfly (~1000 cycles of cover),
// keeping 16 KB/wave outstanding continuously (Little's law -> HBM-bound).
// w1 in LDS (64 KB, quad-swizzled). VGPR ~ 64+64+64+addr, cap 256 via (256,2).
// ---------------------------------------------------------------------------
#define G1_ROWS_PER_BLOCK 128   // 4 waves * 32 rows

__device__ __forceinline__ void g1_load(const float* __restrict__ x, int row0,
                                        int lane, float (&buf)[64]) {
  int r0 = min(row0,     NN - 1);
  int r1 = min(row0 + 1, NN - 1);
  int r2 = min(row0 + 2, NN - 1);
  int r3 = min(row0 + 3, NN - 1);
  const float* p0 = x + (size_t)r0 * FIN + lane;
  const float* p1 = x + (size_t)r1 * FIN + lane;
  const float* p2 = x + (size_t)r2 * FIN + lane;
  const float* p3 = x + (size_t)r3 * FIN + lane;
#pragma unroll
  for (int i = 0; i < 16; ++i) {
    buf[i]      = p0[i * 64];
    buf[16 + i] = p1[i * 64];
    buf[32 + i] = p2[i * 64];
    buf[48 + i] = p3[i * 64];
  }
}

__device__ __forceinline__ void g1_compute_store(const float (&buf)[64],
                                                 const float* w1s, int row0,
                                                 int lane, int sw,
                                                 const float* __restrict__ dis,
                                                 float* __restrict__ xw1s) {
  float acc[64];
#pragma unroll
  for (int t = 0; t < 64; ++t) acc[t] = 0.0f;

#pragma unroll
  for (int i = 0; i < 16; ++i) {
    const float* wr = &w1s[(i * 64 + lane) << 4];
    float xv0 = buf[i], xv1 = buf[16 + i], xv2 = buf[32 + i], xv3 = buf[48 + i];
#pragma unroll
    for (int q = 0; q < 4; ++q) {
      float4 wq = *(const float4*)(wr + ((q ^ sw) << 2));
      int b = q * 4;
      acc[b + 0]      += xv0 * wq.x;
      acc[b + 1]      += xv0 * wq.y;
      acc[b + 2]      += xv0 * wq.z;
      acc[b + 3]      += xv0 * wq.w;
      acc[16 + b + 0] += xv1 * wq.x;
      acc[16 + b + 1] += xv1 * wq.y;
      acc[16 + b + 2] += xv1 * wq.z;
      acc[16 + b + 3] += xv1 * wq.w;
      acc[32 + b + 0] += xv2 * wq.x;
      acc[32 + b + 1] += xv2 * wq.y;
      acc[32 + b + 2] += xv2 * wq.z;
      acc[32 + b + 3] += xv2 * wq.w;
      acc[48 + b + 0] += xv3 * wq.x;
      acc[48 + b + 1] += xv3 * wq.y;
      acc[48 + b + 2] += xv3 * wq.z;
      acc[48 + b + 3] += xv3 * wq.w;
    }
  }

  // butterfly transpose-reduce: lane l ends with (row l>>4, col l&15)
#pragma unroll
  for (int o = 32; o >= 1; o >>= 1) {
    bool up = (lane & o) != 0;
#pragma unroll
    for (int t = 0; t < o; ++t) {
      float send = up ? acc[t] : acc[t + o];
      float recv = __shfl_xor(send, o, 64);
      float keep = up ? acc[t + o] : acc[t];
      acc[t] = keep + recv;
    }
  }

  int grow = row0 + (lane >> 4);
  if (grow < NN) xw1s[grow * HIDN + (lane & 15)] = acc[0] * dis[grow];
}

__global__ __launch_bounds__(256, 2) void k_gemm1(const float* __restrict__ x,
                                                  const float* __restrict__ w1,
                                                  const float* __restrict__ dis,
                                                  float* __restrict__ xw1s) {
  __shared__ __align__(16) float w1s[1024 * 16];
  const float4* w1v = (const float4*)w1;
  for (int idx = threadIdx.x; idx < 4096; idx += 256) {
    int k = idx >> 2, qj = idx & 3;
    int pq = qj ^ ((k >> 1) & 3);               // quad swizzle -> conflict-free
    *(float4*)&w1s[(k << 4) + (pq << 2)] = w1v[idx];
  }
  __syncthreads();

  const int lane = threadIdx.x & 63;
  const int wave = threadIdx.x >> 6;
  const int sw = (lane >> 1) & 3;
  const int wave_row0 = blockIdx.x * G1_ROWS_PER_BLOCK + wave * 32;

  float bufA[64], bufB[64];
  g1_load(x, wave_row0, lane, bufA);

  for (int gg = 0; gg < 4; ++gg) {
    int r_even = wave_row0 + (2 * gg) * 4;
    int r_odd  = wave_row0 + (2 * gg + 1) * 4;
    // even step: prefetch odd group, compute even from bufA
    g1_load(x, r_odd, lane, bufB);
    g1_compute_store(bufA, w1s, r_even, lane, sw, dis, xw1s);
    // odd step: prefetch next even group, compute odd from bufB
    if (gg < 3) g1_load(x, wave_row0 + (2 * gg + 2) * 4, lane, bufA);
    g1_compute_store(bufB, w1s, r_odd, lane, sw, dis, xw1s);
  }
}

// ---------------------------------------------------------------------------
// k_agg: CSR gather-reduce, ONE WAVE PER NODE, unroll-2 (8 gathers in flight).
//   v = dis_i * (sum_e sfs[perm[e]] + sfs[i])
//   MODE 0: out = relu(v + b1[j]) * dis_i  (pre-scaled for next layer)
//   MODE 1: out = v
// ---------------------------------------------------------------------------
template <int MODE>
__global__ __launch_bounds__(256) void k_agg(const int* __restrict__ rowptr,
                                             const int* __restrict__ perm,
                                             const float* __restrict__ dis,
                                             const float* __restrict__ sfs,
                                             const float* __restrict__ b1,
                                             float* __restrict__ out) {
  int g = blockIdx.x * 4 + (threadIdx.x >> 6);     // node (wave id)
  if (g >= NN) return;
  int lane = threadIdx.x & 63;
  int eo = lane >> 4;                              // 0..3
  int j = lane & 15;                               // channel
  int beg = rowptr[g], end = rowptr[g + 1];
  float acc0 = 0.0f, acc1 = 0.0f;
  int e = beg + eo;
  for (; e + 4 < end; e += 8) {
    int s0 = perm[e];
    int s1 = perm[e + 4];
    acc0 += sfs[(size_t)s0 * HIDN + j];
    acc1 += sfs[(size_t)s1 * HIDN + j];
  }
  if (e < end) acc0 += sfs[(size_t)perm[e] * HIDN + j];
  float acc = acc0 + acc1;
  acc += __shfl_xor(acc, 16, 64);
  acc += __shfl_xor(acc, 32, 64);
  if (eo == 0) {
    float di = dis[g];
    float v = di * (acc + sfs[(size_t)g * HIDN + j]);
    if (MODE == 0)
      out[(size_t)g * HIDN + j] = fmaxf(v + b1[j], 0.0f) * di;
    else
      out[(size_t)g * HIDN + j] = v;
  }
}

// ---------------------------------------------------------------------------
// k_fuse2: per row (one wave): h2 = agg2@w2 + b2 -> log_softmax ->
//          * exp(weight_raw) -> @mlp_w + mlp_b -> write d_out + f64 BN stats.
// Shuffle broadcasts replaced by per-wave LDS staging (avbuf/gbuf) and
// float2-interleaved weights (w2p/mlpp): 2 DS ops + 2 FMA per channel PAIR.
// ---------------------------------------------------------------------------
__global__ __launch_bounds__(256) void k_fuse2(const float* __restrict__ agg2,
                                               const float* __restrict__ w2,
                                               const float* __restrict__ b2,
                                               const float* __restrict__ mlpw,
                                               const float* __restrict__ mlpb,
                                               const float* __restrict__ wraw,
                                               float* __restrict__ out,
                                               double* __restrict__ gsum,
                                               double* __restrict__ gsq) {
  __shared__ __align__(16) float2 w2p[8 * CCH];     // (w2[2k][j], w2[2k+1][j])
  __shared__ __align__(16) float2 mlpp[32 * CCH];   // (mlp[2c][j], mlp[2c+1][j])
  __shared__ __align__(16) float avbuf[4][HIDN];
  __shared__ __align__(16) float gbuf[4][CCH];
  __shared__ double reds[256];
  __shared__ double redq[256];
  for (int idx = threadIdx.x; idx < 8 * CCH; idx += 256) {
    int k2 = idx >> 6, j = idx & 63;
    w2p[idx] = make_float2(w2[(2 * k2) * CCH + j], w2[(2 * k2 + 1) * CCH + j]);
  }
  for (int idx = threadIdx.x; idx < 32 * CCH; idx += 256) {
    int c2 = idx >> 6, j = idx & 63;
    mlpp[idx] = make_float2(mlpw[(2 * c2) * CCH + j], mlpw[(2 * c2 + 1) * CCH + j]);
  }
  __syncthreads();

  const int lane = threadIdx.x & 63;
  const int wave = threadIdx.x >> 6;
  const int j = lane;
  const float b2j = b2[j];
  const float mbj = mlpb[j];
  const int gw = blockIdx.x * 4 + wave;
  const int nw = gridDim.x * 4;

  double sum = 0.0, sq = 0.0;
  for (int i = gw; i < NN; i += nw) {
    float av = agg2[(size_t)i * HIDN + (lane & 15)];
    if (lane < HIDN) avbuf[wave][lane] = av;

    float2 h2p = make_float2(0.0f, 0.0f);
#pragma unroll
    for (int k2 = 0; k2 < 8; ++k2) {
      float2 a = *(const float2*)&avbuf[wave][2 * k2];   // broadcast read
      float2 wv = w2p[k2 * CCH + j];
      h2p.x = fmaf(a.x, wv.x, h2p.x);
      h2p.y = fmaf(a.y, wv.y, h2p.y);
    }
    float h2 = h2p.x + h2p.y + b2j;

    float mx = h2;
#pragma unroll
    for (int o = 32; o >= 1; o >>= 1) mx = fmaxf(mx, __shfl_xor(mx, o, 64));
    float ex = __expf(h2 - mx);
    float se = ex;
#pragma unroll
    for (int o = 32; o >= 1; o >>= 1) se += __shfl_xor(se, o, 64);
    float lsm = h2 - mx - __logf(se);

    float gg = __expf(wraw[i]) * lsm;
    gbuf[wave][j] = gg;

    float2 mp = make_float2(0.0f, 0.0f);
#pragma unroll
    for (int c2 = 0; c2 < 32; ++c2) {
      float2 gv = *(const float2*)&gbuf[wave][2 * c2];   // broadcast read
      float2 wv = mlpp[c2 * CCH + j];
      mp.x = fmaf(gv.x, wv.x, mp.x);
      mp.y = fmaf(gv.y, wv.y, mp.y);
    }
    float m = mp.x + mp.y + mbj;

    out[(size_t)i * CCH + j] = m;
    sum += (double)m;
    sq = fma((double)m, (double)m, sq);
  }

  reds[threadIdx.x] = sum;
  redq[threadIdx.x] = sq;
  __syncthreads();
  if (threadIdx.x < 64) {
    double s = reds[threadIdx.x] + reds[threadIdx.x + 64] +
               reds[threadIdx.x + 128] + reds[threadIdx.x + 192];
    double q = redq[threadIdx.x] + redq[threadIdx.x + 64] +
               redq[threadIdx.x + 128] + redq[threadIdx.x + 192];
    atomicAdd(&gsum[threadIdx.x], s);
    atomicAdd(&gsq[threadIdx.x], q);
  }
}

// ---------------------------------------------------------------------------
// k_stats: finalize BN params in double (no cancellation)
// ---------------------------------------------------------------------------
__global__ void k_stats(const double* __restrict__ gsum,
                        const double* __restrict__ gsq,
                        const float* __restrict__ gamma,
                        const float* __restrict__ beta,
                        float* __restrict__ bnp) {
  int j = threadIdx.x;
  if (j >= CCH) return;
  const double inv_n = 1.0 / (double)NN;
  double mean = gsum[j] * inv_n;
  double var = gsq[j] * inv_n - mean * mean;
  float sc = (float)(rsqrt(var + (double)BNEPS)) * gamma[j];
  bnp[j] = (float)mean;
  bnp[CCH + j] = sc;
  bnp[2 * CCH + j] = beta[j];
}

// ---------------------------------------------------------------------------
// k_out: BN apply + final log_softmax, in-place on d_out (wave per row)
// ---------------------------------------------------------------------------
__global__ __launch_bounds__(256) void k_out(float* __restrict__ out,
                                             const float* __restrict__ bnp) {
  const int lane = threadIdx.x & 63;
  const int wave = threadIdx.x >> 6;
  const int j = lane;
  const float mean = bnp[j];
  const float sc = bnp[CCH + j];
  const float bt = bnp[2 * CCH + j];
  const int gw = blockIdx.x * 4 + wave;
  const int nw = gridDim.x * 4;
  for (int i = gw; i < NN; i += nw) {
    float m = out[(size_t)i * CCH + j];
    float y = fmaf(m - mean, sc, bt);
    float mx = y;
#pragma unroll
    for (int o = 32; o >= 1; o >>= 1) mx = fmaxf(mx, __shfl_xor(mx, o, 64));
    float ex = __expf(y - mx);
    float se = ex;
#pragma unroll
    for (int o = 32; o >= 1; o >>= 1) se += __shfl_xor(se, o, 64);
    out[(size_t)i * CCH + j] = y - mx - __logf(se);
  }
}

// ---------------------------------------------------------------------------
extern "C" void kernel_launch(void* const* d_in, const int* in_sizes, int n_in,
                              void* d_out, int out_size, void* d_ws, size_t ws_size,
                              hipStream_t stream) {
  const float* x     = (const float*)d_in[0];
  const int*   ei    = (const int*)d_in[1];
  const float* w1    = (const float*)d_in[2];
  const float* b1    = (const float*)d_in[3];
  const float* w2    = (const float*)d_in[4];
  const float* b2    = (const float*)d_in[5];
  const float* mlpw  = (const float*)d_in[6];
  const float* mlpb  = (const float*)d_in[7];
  const float* gamma = (const float*)d_in[8];
  const float* beta  = (const float*)d_in[9];
  const float* wraw  = (const float*)d_in[10];
  float* out = (float*)d_out;

  // workspace carve (256B aligned slots)
  char* w = (char*)d_ws;
  size_t off = 0;
  auto take = [&](size_t bytes) -> void* {
    void* p = w + off;
    off = (off + bytes + 255) & ~(size_t)255;
    return p;
  };
  unsigned* deg    = (unsigned*)take((size_t)NN * 4);
  float*    dis    = (float*)take((size_t)NN * 4);
  unsigned* exc    = (unsigned*)take((size_t)NN * 4);
  unsigned* bsum   = (unsigned*)take((size_t)NB * 4);
  unsigned* boff   = (unsigned*)take((size_t)NB * 4);
  int*      rowptr = (int*)take((size_t)(NN + 1) * 4);
  int*      cur    = (int*)take((size_t)NN * 4);
  int*      perm   = (int*)take((size_t)EE * 4);
  float*    xw1s   = (float*)take((size_t)NN * HIDN * 4);
  float*    rh1s   = (float*)take((size_t)NN * HIDN * 4);
  float*    agg2   = (float*)take((size_t)NN * HIDN * 4);
  double*   gsum   = (double*)take(CCH * 8);
  double*   gsq    = (double*)take(CCH * 8);
  float*    bnp    = (float*)take(3 * CCH * 4);
  (void)ws_size; (void)n_in; (void)in_sizes; (void)out_size;

  hipMemsetAsync(deg, 0, (size_t)NN * 4, stream);
  hipMemsetAsync(gsum, 0, CCH * 8, stream);
  hipMemsetAsync(gsq, 0, CCH * 8, stream);

  // CSR build: XCD-partitioned histogram -> scan -> XCD-partitioned place
  k_hist<<<2048, 256, 0, stream>>>(ei, deg);
  k_scan_part<<<NB, 256, 0, stream>>>(deg, exc, bsum);
  k_scan_boff<<<1, 512, 0, stream>>>(bsum, boff);
  k_scan_final<<<(NN + 256) / 256 + 1, 256, 0, stream>>>(exc, boff, deg, rowptr, cur, dis);
  k_place<<<2048, 256, 0, stream>>>(ei, cur, perm);

  // dense transform (pipelined, pre-scaled) + 2 agg passes + streaming tail
  k_gemm1<<<(NN + G1_ROWS_PER_BLOCK - 1) / G1_ROWS_PER_BLOCK, 256, 0, stream>>>(
      x, w1, dis, xw1s);
  k_agg<0><<<(NN + 3) / 4, 256, 0, stream>>>(rowptr, perm, dis, xw1s, b1, rh1s);
  k_agg<1><<<(NN + 3) / 4, 256, 0, stream>>>(rowptr, perm, dis, rh1s, b1, agg2);
  k_fuse2<<<2048, 256, 0, stream>>>(agg2, w2, b2, mlpw, mlpb, wraw, out, gsum, gsq);
  k_stats<<<1, 64, 0, stream>>>(gsum, gsq, gamma, beta, bnp);
  k_out<<<1024, 256, 0, stream>>>(out, bnp);
}

// Round 7
// 593.632 us; speedup vs baseline: 2.5877x; 2.5877x over previous
//
#include <hip/hip_runtime.h>
#include <math.h>

// Problem constants (fixed by the reference)
#define NN   100000
#define FIN  1024
#define HIDN 16
#define CCH  64
#define EE   3200000
#define BNEPS 1e-5f
#define NB   ((NN + 255) / 256)   // 391 scan blocks
#define NPART 8                   // XCD count
#define PSZ  (NN / NPART)         // 12500 nodes per partition

// ---------------------------------------------------------------------------
// k_hist: XCD-partitioned in-degree histogram (atomics stay in one XCD's L2)
// ---------------------------------------------------------------------------
__global__ __launch_bounds__(256) void k_hist(const int* __restrict__ ei,
                                              unsigned* __restrict__ deg) {
  int p = blockIdx.x & 7;
  int blk = blockIdx.x >> 3;
  int nblk = gridDim.x >> 3;
  int lo = p * PSZ, hi = lo + PSZ;
  for (int e = blk * 256 + threadIdx.x; e < EE; e += nblk * 256) {
    int d = ei[EE + e];
    if (d >= lo && d < hi) atomicAdd(&deg[d], 1u);
  }
}

// ---------------------------------------------------------------------------
// exclusive scan of deg -> rowptr (+ cur copy, + dis = rsqrt(deg+1))
// ---------------------------------------------------------------------------
__global__ __launch_bounds__(256) void k_scan_part(const unsigned* __restrict__ deg,
                                                   unsigned* __restrict__ exc,
                                                   unsigned* __restrict__ bsum) {
  __shared__ unsigned s[256];
  int t = threadIdx.x, i = blockIdx.x * 256 + t;
  unsigned v = (i < NN) ? deg[i] : 0u;
  s[t] = v;
  __syncthreads();
#pragma unroll
  for (int off = 1; off < 256; off <<= 1) {
    unsigned u = (t >= off) ? s[t - off] : 0u;
    __syncthreads();
    s[t] += u;
    __syncthreads();
  }
  if (i < NN) exc[i] = s[t] - v;
  if (t == 255) bsum[blockIdx.x] = s[255];
}

__global__ __launch_bounds__(512) void k_scan_boff(const unsigned* __restrict__ bsum,
                                                   unsigned* __restrict__ boff) {
  __shared__ unsigned s[512];
  int t = threadIdx.x;
  unsigned v = (t < NB) ? bsum[t] : 0u;
  s[t] = v;
  __syncthreads();
#pragma unroll
  for (int off = 1; off < 512; off <<= 1) {
    unsigned u = (t >= off) ? s[t - off] : 0u;
    __syncthreads();
    s[t] += u;
    __syncthreads();
  }
  if (t < NB) boff[t] = s[t] - v;
}

__global__ __launch_bounds__(256) void k_scan_final(const unsigned* __restrict__ exc,
                                                    const unsigned* __restrict__ boff,
                                                    const unsigned* __restrict__ deg,
                                                    int* __restrict__ rowptr,
                                                    int* __restrict__ cur,
                                                    float* __restrict__ dis) {
  int i = blockIdx.x * 256 + threadIdx.x;
  if (i < NN) {
    int r = (int)(boff[i >> 8] + exc[i]);
    rowptr[i] = r;
    cur[i] = r;
    dis[i] = rsqrtf((float)(deg[i] + 1u));
  } else if (i == NN) {
    rowptr[NN] = EE;
  }
}

// ---------------------------------------------------------------------------
// k_place: XCD-partitioned bucket placement (cur + perm slices L2-local)
// ---------------------------------------------------------------------------
__global__ __launch_bounds__(256) void k_place(const int* __restrict__ ei,
                                               int* __restrict__ cur,
                                               int* __restrict__ perm) {
  int p = blockIdx.x & 7;
  int blk = blockIdx.x >> 3;
  int nblk = gridDim.x >> 3;
  int lo = p * PSZ, hi = lo + PSZ;
  for (int e = blk * 256 + threadIdx.x; e < EE; e += nblk * 256) {
    int d = ei[EE + e];
    if (d >= lo && d < hi) {
      int s = ei[e];
      int slot = atomicAdd(&cur[d], 1);
      perm[slot] = s;
    }
  }
}

// ---------------------------------------------------------------------------
// k_gemm1: xw1s[N,16] = (x[N,1024] @ w1[1024,16]) * dis_i  (pre-scaled)
// ROUND-5 STRUCTURE (single buffer): per 4-row group, all 64 x-loads issued
// into registers (nontemporal: x is stream-once, keep L2/L3 clean) before
// the FMA phase; cross-wave overlap (8 waves/CU) hides the phase gaps.
// VGPR ~ 64(buf)+64(acc)+misc < 256 cap -> no spill (round-6 lesson: double
// buffering spills at VGPR 128 cap and costs 6x).
// w1 in LDS (64 KB, quad-swizzled). Butterfly transpose-reduce at the end.
// ---------------------------------------------------------------------------
#define G1_ROWS_PER_BLOCK 128   // 4 waves * 32 rows
__global__ __launch_bounds__(256, 2) void k_gemm1(const float* __restrict__ x,
                                                  const float* __restrict__ w1,
                                                  const float* __restrict__ dis,
                                                  float* __restrict__ xw1s) {
  __shared__ __align__(16) float w1s[1024 * 16];
  const float4* w1v = (const float4*)w1;
  for (int idx = threadIdx.x; idx < 4096; idx += 256) {
    int k = idx >> 2, qj = idx & 3;
    int pq = qj ^ ((k >> 1) & 3);               // quad swizzle -> conflict-free
    *(float4*)&w1s[(k << 4) + (pq << 2)] = w1v[idx];
  }
  __syncthreads();

  const int lane = threadIdx.x & 63;
  const int wave = threadIdx.x >> 6;
  const int sw = (lane >> 1) & 3;
  const int wave_row0 = blockIdx.x * G1_ROWS_PER_BLOCK + wave * 32;

  for (int g = 0; g < 8; ++g) {
    int row0 = wave_row0 + g * 4;
    if (row0 >= NN) break;
    int r0 = row0;
    int r1 = min(row0 + 1, NN - 1);
    int r2 = min(row0 + 2, NN - 1);
    int r3 = min(row0 + 3, NN - 1);

    const float* p0 = x + (size_t)r0 * FIN + lane;
    const float* p1 = x + (size_t)r1 * FIN + lane;
    const float* p2 = x + (size_t)r2 * FIN + lane;
    const float* p3 = x + (size_t)r3 * FIN + lane;

    // ---- load phase: all 64 loads in flight before any dependent use ----
    float xa[16], xb[16], xc[16], xd[16];
#pragma unroll
    for (int i = 0; i < 16; ++i) {
      xa[i] = __builtin_nontemporal_load(p0 + i * 64);
      xb[i] = __builtin_nontemporal_load(p1 + i * 64);
      xc[i] = __builtin_nontemporal_load(p2 + i * 64);
      xd[i] = __builtin_nontemporal_load(p3 + i * 64);
    }

    float acc[64];
#pragma unroll
    for (int t = 0; t < 64; ++t) acc[t] = 0.0f;

    // ---- compute phase ----
#pragma unroll
    for (int i = 0; i < 16; ++i) {
      const float* wr = &w1s[(i * 64 + lane) << 4];
      float xv0 = xa[i], xv1 = xb[i], xv2 = xc[i], xv3 = xd[i];
#pragma unroll
      for (int q = 0; q < 4; ++q) {
        float4 wq = *(const float4*)(wr + ((q ^ sw) << 2));
        int b = q * 4;
        acc[b + 0]      += xv0 * wq.x;
        acc[b + 1]      += xv0 * wq.y;
        acc[b + 2]      += xv0 * wq.z;
        acc[b + 3]      += xv0 * wq.w;
        acc[16 + b + 0] += xv1 * wq.x;
        acc[16 + b + 1] += xv1 * wq.y;
        acc[16 + b + 2] += xv1 * wq.z;
        acc[16 + b + 3] += xv1 * wq.w;
        acc[32 + b + 0] += xv2 * wq.x;
        acc[32 + b + 1] += xv2 * wq.y;
        acc[32 + b + 2] += xv2 * wq.z;
        acc[32 + b + 3] += xv2 * wq.w;
        acc[48 + b + 0] += xv3 * wq.x;
        acc[48 + b + 1] += xv3 * wq.y;
        acc[48 + b + 2] += xv3 * wq.z;
        acc[48 + b + 3] += xv3 * wq.w;
      }
    }

    // butterfly transpose-reduce: lane l ends with (row l>>4, col l&15)
#pragma unroll
    for (int o = 32; o >= 1; o >>= 1) {
      bool up = (lane & o) != 0;
#pragma unroll
      for (int t = 0; t < o; ++t) {
        float send = up ? acc[t] : acc[t + o];
        float recv = __shfl_xor(send, o, 64);
        float keep = up ? acc[t + o] : acc[t];
        acc[t] = keep + recv;
      }
    }

    int grow = row0 + (lane >> 4);
    if (grow < NN) xw1s[grow * HIDN + (lane & 15)] = acc[0] * dis[grow];
  }
}

// ---------------------------------------------------------------------------
// k_agg: CSR gather-reduce, ONE WAVE PER NODE, unroll-2 (8 gathers in flight).
//   v = dis_i * (sum_e sfs[perm[e]] + sfs[i])
//   MODE 0: out = relu(v + b1[j]) * dis_i  (pre-scaled for next layer)
//   MODE 1: out = v
// ---------------------------------------------------------------------------
template <int MODE>
__global__ __launch_bounds__(256) void k_agg(const int* __restrict__ rowptr,
                                             const int* __restrict__ perm,
                                             const float* __restrict__ dis,
                                             const float* __restrict__ sfs,
                                             const float* __restrict__ b1,
                                             float* __restrict__ out) {
  int g = blockIdx.x * 4 + (threadIdx.x >> 6);     // node (wave id)
  if (g >= NN) return;
  int lane = threadIdx.x & 63;
  int eo = lane >> 4;                              // 0..3
  int j = lane & 15;                               // channel
  int beg = rowptr[g], end = rowptr[g + 1];
  float acc0 = 0.0f, acc1 = 0.0f;
  int e = beg + eo;
  for (; e + 4 < end; e += 8) {
    int s0 = perm[e];
    int s1 = perm[e + 4];
    acc0 += sfs[(size_t)s0 * HIDN + j];
    acc1 += sfs[(size_t)s1 * HIDN + j];
  }
  if (e < end) acc0 += sfs[(size_t)perm[e] * HIDN + j];
  float acc = acc0 + acc1;
  acc += __shfl_xor(acc, 16, 64);
  acc += __shfl_xor(acc, 32, 64);
  if (eo == 0) {
    float di = dis[g];
    float v = di * (acc + sfs[(size_t)g * HIDN + j]);
    if (MODE == 0)
      out[(size_t)g * HIDN + j] = fmaxf(v + b1[j], 0.0f) * di;
    else
      out[(size_t)g * HIDN + j] = v;
  }
}

// ---------------------------------------------------------------------------
// k_fuse2: per row (one wave): h2 = agg2@w2 + b2 -> log_softmax ->
//          * exp(weight_raw) -> @mlp_w + mlp_b -> write d_out + f64 BN stats.
// Shuffle broadcasts replaced by per-wave LDS staging (avbuf/gbuf) and
// float2-interleaved weights (w2p/mlpp): 2 DS ops + 2 FMA per channel PAIR.
// ---------------------------------------------------------------------------
__global__ __launch_bounds__(256) void k_fuse2(const float* __restrict__ agg2,
                                               const float* __restrict__ w2,
                                               const float* __restrict__ b2,
                                               const float* __restrict__ mlpw,
                                               const float* __restrict__ mlpb,
                                               const float* __restrict__ wraw,
                                               float* __restrict__ out,
                                               double* __restrict__ gsum,
                                               double* __restrict__ gsq) {
  __shared__ __align__(16) float2 w2p[8 * CCH];     // (w2[2k][j], w2[2k+1][j])
  __shared__ __align__(16) float2 mlpp[32 * CCH];   // (mlp[2c][j], mlp[2c+1][j])
  __shared__ __align__(16) float avbuf[4][HIDN];
  __shared__ __align__(16) float gbuf[4][CCH];
  __shared__ double reds[256];
  __shared__ double redq[256];
  for (int idx = threadIdx.x; idx < 8 * CCH; idx += 256) {
    int k2 = idx >> 6, j = idx & 63;
    w2p[idx] = make_float2(w2[(2 * k2) * CCH + j], w2[(2 * k2 + 1) * CCH + j]);
  }
  for (int idx = threadIdx.x; idx < 32 * CCH; idx += 256) {
    int c2 = idx >> 6, j = idx & 63;
    mlpp[idx] = make_float2(mlpw[(2 * c2) * CCH + j], mlpw[(2 * c2 + 1) * CCH + j]);
  }
  __syncthreads();

  const int lane = threadIdx.x & 63;
  const int wave = threadIdx.x >> 6;
  const int j = lane;
  const float b2j = b2[j];
  const float mbj = mlpb[j];
  const int gw = blockIdx.x * 4 + wave;
  const int nw = gridDim.x * 4;

  double sum = 0.0, sq = 0.0;
  for (int i = gw; i < NN; i += nw) {
    float av = agg2[(size_t)i * HIDN + (lane & 15)];
    if (lane < HIDN) avbuf[wave][lane] = av;

    float2 h2p = make_float2(0.0f, 0.0f);
#pragma unroll
    for (int k2 = 0; k2 < 8; ++k2) {
      float2 a = *(const float2*)&avbuf[wave][2 * k2];   // broadcast read
      float2 wv = w2p[k2 * CCH + j];
      h2p.x = fmaf(a.x, wv.x, h2p.x);
      h2p.y = fmaf(a.y, wv.y, h2p.y);
    }
    float h2 = h2p.x + h2p.y + b2j;

    float mx = h2;
#pragma unroll
    for (int o = 32; o >= 1; o >>= 1) mx = fmaxf(mx, __shfl_xor(mx, o, 64));
    float ex = __expf(h2 - mx);
    float se = ex;
#pragma unroll
    for (int o = 32; o >= 1; o >>= 1) se += __shfl_xor(se, o, 64);
    float lsm = h2 - mx - __logf(se);

    float gg = __expf(wraw[i]) * lsm;
    gbuf[wave][j] = gg;

    float2 mp = make_float2(0.0f, 0.0f);
#pragma unroll
    for (int c2 = 0; c2 < 32; ++c2) {
      float2 gv = *(const float2*)&gbuf[wave][2 * c2];   // broadcast read
      float2 wv = mlpp[c2 * CCH + j];
      mp.x = fmaf(gv.x, wv.x, mp.x);
      mp.y = fmaf(gv.y, wv.y, mp.y);
    }
    float m = mp.x + mp.y + mbj;

    out[(size_t)i * CCH + j] = m;
    sum += (double)m;
    sq = fma((double)m, (double)m, sq);
  }

  reds[threadIdx.x] = sum;
  redq[threadIdx.x] = sq;
  __syncthreads();
  if (threadIdx.x < 64) {
    double s = reds[threadIdx.x] + reds[threadIdx.x + 64] +
               reds[threadIdx.x + 128] + reds[threadIdx.x + 192];
    double q = redq[threadIdx.x] + redq[threadIdx.x + 64] +
               redq[threadIdx.x + 128] + redq[threadIdx.x + 192];
    atomicAdd(&gsum[threadIdx.x], s);
    atomicAdd(&gsq[threadIdx.x], q);
  }
}

// ---------------------------------------------------------------------------
// k_stats: finalize BN params in double (no cancellation)
// ---------------------------------------------------------------------------
__global__ void k_stats(const double* __restrict__ gsum,
                        const double* __restrict__ gsq,
                        const float* __restrict__ gamma,
                        const float* __restrict__ beta,
                        float* __restrict__ bnp) {
  int j = threadIdx.x;
  if (j >= CCH) return;
  const double inv_n = 1.0 / (double)NN;
  double mean = gsum[j] * inv_n;
  double var = gsq[j] * inv_n - mean * mean;
  float sc = (float)(rsqrt(var + (double)BNEPS)) * gamma[j];
  bnp[j] = (float)mean;
  bnp[CCH + j] = sc;
  bnp[2 * CCH + j] = beta[j];
}

// ---------------------------------------------------------------------------
// k_out: BN apply + final log_softmax, in-place on d_out (wave per row)
// ---------------------------------------------------------------------------
__global__ __launch_bounds__(256) void k_out(float* __restrict__ out,
                                             const float* __restrict__ bnp) {
  const int lane = threadIdx.x & 63;
  const int wave = threadIdx.x >> 6;
  const int j = lane;
  const float mean = bnp[j];
  const float sc = bnp[CCH + j];
  const float bt = bnp[2 * CCH + j];
  const int gw = blockIdx.x * 4 + wave;
  const int nw = gridDim.x * 4;
  for (int i = gw; i < NN; i += nw) {
    float m = out[(size_t)i * CCH + j];
    float y = fmaf(m - mean, sc, bt);
    float mx = y;
#pragma unroll
    for (int o = 32; o >= 1; o >>= 1) mx = fmaxf(mx, __shfl_xor(mx, o, 64));
    float ex = __expf(y - mx);
    float se = ex;
#pragma unroll
    for (int o = 32; o >= 1; o >>= 1) se += __shfl_xor(se, o, 64);
    out[(size_t)i * CCH + j] = y - mx - __logf(se);
  }
}

// ---------------------------------------------------------------------------
extern "C" void kernel_launch(void* const* d_in, const int* in_sizes, int n_in,
                              void* d_out, int out_size, void* d_ws, size_t ws_size,
                              hipStream_t stream) {
  const float* x     = (const float*)d_in[0];
  const int*   ei    = (const int*)d_in[1];
  const float* w1    = (const float*)d_in[2];
  const float* b1    = (const float*)d_in[3];
  const float* w2    = (const float*)d_in[4];
  const float* b2    = (const float*)d_in[5];
  const float* mlpw  = (const float*)d_in[6];
  const float* mlpb  = (const float*)d_in[7];
  const float* gamma = (const float*)d_in[8];
  const float* beta  = (const float*)d_in[9];
  const float* wraw  = (const float*)d_in[10];
  float* out = (float*)d_out;

  // workspace carve (256B aligned slots)
  char* w = (char*)d_ws;
  size_t off = 0;
  auto take = [&](size_t bytes) -> void* {
    void* p = w + off;
    off = (off + bytes + 255) & ~(size_t)255;
    return p;
  };
  unsigned* deg    = (unsigned*)take((size_t)NN * 4);
  float*    dis    = (float*)take((size_t)NN * 4);
  unsigned* exc    = (unsigned*)take((size_t)NN * 4);
  unsigned* bsum   = (unsigned*)take((size_t)NB * 4);
  unsigned* boff   = (unsigned*)take((size_t)NB * 4);
  int*      rowptr = (int*)take((size_t)(NN + 1) * 4);
  int*      cur    = (int*)take((size_t)NN * 4);
  int*      perm   = (int*)take((size_t)EE * 4);
  float*    xw1s   = (float*)take((size_t)NN * HIDN * 4);
  float*    rh1s   = (float*)take((size_t)NN * HIDN * 4);
  float*    agg2   = (float*)take((size_t)NN * HIDN * 4);
  double*   gsum   = (double*)take(CCH * 8);
  double*   gsq    = (double*)take(CCH * 8);
  float*    bnp    = (float*)take(3 * CCH * 4);
  (void)ws_size; (void)n_in; (void)in_sizes; (void)out_size;

  hipMemsetAsync(deg, 0, (size_t)NN * 4, stream);
  hipMemsetAsync(gsum, 0, CCH * 8, stream);
  hipMemsetAsync(gsq, 0, CCH * 8, stream);

  // CSR build: XCD-partitioned histogram -> scan -> XCD-partitioned place
  k_hist<<<2048, 256, 0, stream>>>(ei, deg);
  k_scan_part<<<NB, 256, 0, stream>>>(deg, exc, bsum);
  k_scan_boff<<<1, 512, 0, stream>>>(bsum, boff);
  k_scan_final<<<(NN + 256) / 256 + 1, 256, 0, stream>>>(exc, boff, deg, rowptr, cur, dis);
  k_place<<<2048, 256, 0, stream>>>(ei, cur, perm);

  // dense transform (pre-scaled) + 2 agg passes + streaming tail
  k_gemm1<<<(NN + G1_ROWS_PER_BLOCK - 1) / G1_ROWS_PER_BLOCK, 256, 0, stream>>>(
      x, w1, dis, xw1s);
  k_agg<0><<<(NN + 3) / 4, 256, 0, stream>>>(rowptr, perm, dis, xw1s, b1, rh1s);
  k_agg<1><<<(NN + 3) / 4, 256, 0, stream>>>(rowptr, perm, dis, rh1s, b1, agg2);
  k_fuse2<<<2048, 256, 0, stream>>>(agg2, w2, b2, mlpw, mlpb, wraw, out, gsum, gsq);
  k_stats<<<1, 64, 0, stream>>>(gsum, gsq, gamma, beta, bnp);
  k_out<<<1024, 256, 0, stream>>>(out, bnp);
}